// Round 1
// baseline (5978.501 us; speedup 1.0000x reference)
//
#include <hip/hip_runtime.h>
#include <hip/hip_bf16.h>

#define B_ 128
#define T_ 512
#define I_ 64
#define H_ 1024
#define O_ 12
#define HSTEP (H_ * B_)   // 131072 bf16 elements per timestep plane of hP
#define XSTEP (I_ * B_)   // 8192 bf16 elements per timestep of xPhi
#define TIMEOUT 2000      // fast-spin passes before sticky per-wave agent fallback
#define SENT 0x7FC07FC0u  // bf16 NaN pair: tanh output (finite, |v|<=1) can never produce it

typedef __attribute__((ext_vector_type(8))) short bf16x8;
typedef __attribute__((ext_vector_type(4))) float f32x4;

#define MFMA16 __builtin_amdgcn_mfma_f32_16x16x32_bf16

__device__ __forceinline__ float bf2f(unsigned short s) {
  unsigned u = ((unsigned)s) << 16; float f; __builtin_memcpy(&f, &u, 4); return f;
}
__device__ __forceinline__ unsigned short f2bf(float f) {
  unsigned u; __builtin_memcpy(&u, &f, 4);
  u += 0x7fffu + ((u >> 16) & 1u);   // RNE (finite inputs only here)
  return (unsigned short)(u >> 16);
}

// ---- proven agent-scope (LLC) primitives: slow-path pair ----
__device__ __forceinline__ unsigned long long ldA64(const unsigned long long* p) {
  return __hip_atomic_load(p, __ATOMIC_RELAXED, __HIP_MEMORY_SCOPE_AGENT);
}
__device__ __forceinline__ void stA32(unsigned* p, unsigned v) {
  __hip_atomic_store(p, v, __ATOMIC_RELAXED, __HIP_MEMORY_SCOPE_AGENT);
}

// ---- XCD-local primitives (sc0: bypass L1, served by this XCD's L2): fast pair ----
__device__ __forceinline__ void store32_sc0(unsigned* p, unsigned v) {
  asm volatile("global_store_dword %0, %1, off sc0" :: "v"(p), "v"(v) : "memory");
}
__device__ __forceinline__ bf16x8 load16_sc0(const void* p) {
  bf16x8 v;
  asm volatile("global_load_dwordx4 %0, %1, off sc0" : "=v"(v) : "v"(p));
  return v;
}
__device__ __forceinline__ void waitv8(bf16x8& v0, bf16x8& v1, bf16x8& v2, bf16x8& v3,
                                       bf16x8& v4, bf16x8& v5, bf16x8& v6, bf16x8& v7) {
  asm volatile("s_waitcnt vmcnt(0)"
               : "+v"(v0), "+v"(v1), "+v"(v2), "+v"(v3),
                 "+v"(v4), "+v"(v5), "+v"(v6), "+v"(v7) :: "memory");
}

// ---- prep: sentinel-poison the full hP history (the data IS the ready flag) ----
__global__ void prep_fill(unsigned short* __restrict__ hP) {
  const size_t stride = (size_t)gridDim.x * 256 * 8;
  size_t idx = ((size_t)blockIdx.x * 256 + threadIdx.x) * 8;
  const short s = (short)0x7FC0;
  bf16x8 v = {s, s, s, s, s, s, s, s};
  const size_t total = (size_t)T_ * HSTEP;
  for (; idx < total; idx += stride) *(bf16x8*)(hP + idx) = v;
}

// ---- prep: x[b][t][i] fp32 -> pack-layout bf16 plane xPhi[t][i/8][b][i%8] ----
__global__ void prep_xp(const float* __restrict__ x,
                        unsigned short* __restrict__ xPhi) {
  const int t = blockIdx.x;
  for (int u = threadIdx.x; u < 1024; u += 256) {   // u = ib*128 + b
    const int ib = u >> 7, b = u & 127;
    const float* src = x + ((size_t)b * T_ + t) * I_ + ib * 8;
    bf16x8 hi;
    #pragma unroll
    for (int j = 0; j < 8; ++j) hi[j] = (short)f2bf(src[j]);
    *(bf16x8*)(xPhi + ((size_t)t * 1024 + u) * 8) = hi;
  }
}

// ---- prep: W_out transposed/padded WoT[k][16] ----
__global__ void prep_misc(const float* __restrict__ W_out, float* __restrict__ WoT) {
  const int idx = blockIdx.x * 256 + threadIdx.x;   // 64 blocks -> 16384 threads
  const int k = idx >> 4, s = idx & 15;
  float v = 0.0f;
  if (s < 6)                 v = W_out[s * H_ + k];
  else if (s >= 8 && s < 14) v = W_out[(s - 2) * H_ + k];
  WoT[idx] = v;
}

// ---- persistent MFMA recurrence ----
// g = bid&7 (batch group; XCD-pure under round-robin dispatch), rg = bid>>3.
// h exchange is DATA-DRIVEN: producers dual-store packed bf16 pairs straight
// into hP plane t (sc0 for same-XCD L2 + agent write-through to LLC); consumers
// spin on their own 16B granules until all 4 dwords are non-sentinel. hP is a
// T-deep write-once ring, so a stale read can only show the sentinel (delay),
// never wrong data. No flags, no vmcnt drains, one barrier per step (part[] is
// parity double-buffered). Per-wave bounded timeout -> sticky agent-scope loads
// (proven LLC pair) keeps any cross-XCD placement correct.
__global__ __launch_bounds__(256, 1) void rnn_mfma(
    const float* __restrict__ W_ih, const float* __restrict__ W_hh,
    const float* __restrict__ b_ih, const float* __restrict__ b_hh,
    const unsigned short* __restrict__ xPhi, unsigned short* __restrict__ hP)
{
  __shared__ float part[2][4][544];   // [t&1][wave][8 rows x 68 padded]
  __shared__ float biasS[32];
  const int tid = threadIdx.x, bid = blockIdx.x;
  const int wave = tid >> 6, lane = tid & 63, quad = lane >> 4, ln = lane & 15;
  const int g = bid & 7, rg = bid >> 3;
  const int r0 = rg * 32, b0 = g * 16;
  if (tid < 32) biasS[tid] = b_ih[r0 + tid] + b_hh[r0 + tid];

  // A-frags for W_hh (hi/lo split -> fp32-grade W precision), loaded once.
  bf16x8 ahhi[2][8], ahlo[2][8];
  #pragma unroll
  for (int mt = 0; mt < 2; ++mt)
    #pragma unroll
    for (int kt = 0; kt < 8; ++kt) {
      const float* wp = W_hh + (size_t)(r0 + mt * 16 + ln) * H_
                        + wave * 256 + kt * 32 + quad * 8;
      #pragma unroll
      for (int j = 0; j < 8; ++j) {
        float v = wp[j];
        unsigned short h = f2bf(v);
        ahhi[mt][kt][j] = (short)h;
        ahlo[mt][kt][j] = (short)f2bf(v - bf2f(h));
      }
    }
  // A-frags for W_ih: waves 0,1 own the two x K-tiles (i in [32w,32w+32)).
  bf16x8 axhi[2], axlo[2];
  if (wave < 2)
    #pragma unroll
    for (int mt = 0; mt < 2; ++mt) {
      const float* wp = W_ih + (size_t)(r0 + mt * 16 + ln) * I_
                        + wave * 32 + quad * 8;
      #pragma unroll
      for (int j = 0; j < 8; ++j) {
        float v = wp[j];
        unsigned short h = f2bf(v);
        axhi[mt][j] = (short)h;
        axlo[mt][j] = (short)f2bf(v - bf2f(h));
      }
    }
  __syncthreads();

  const int bcol = b0 + ln;
  // Consumer granule base within a plane (shorts). Wave's K-quarter: octet
  // K8 = wave*32 + kt*4 + quad, batch bcol; kt stride = 4*B_*8 = 4096 shorts.
  const size_t cbase = ((size_t)(wave * 32 + quad) * B_ + bcol) * 8;

  f32x4 xacc0 = {0.f, 0.f, 0.f, 0.f}, xacc1 = {0.f, 0.f, 0.f, 0.f};
  auto computeX = [&](int t) {      // x-contribution for step t (waves 0,1)
    if (wave < 2) {
      const size_t xo = (((size_t)t * 8 + wave * 4 + quad) * B_ + bcol) * 8;
      bf16x8 bxh = *(const bf16x8*)(xPhi + xo);
      f32x4 t0 = {0.f, 0.f, 0.f, 0.f}, t1 = {0.f, 0.f, 0.f, 0.f};
      t0 = MFMA16(axhi[0], bxh, t0, 0, 0, 0);
      t0 = MFMA16(axlo[0], bxh, t0, 0, 0, 0);
      t1 = MFMA16(axhi[1], bxh, t1, 0, 0, 0);
      t1 = MFMA16(axlo[1], bxh, t1, 0, 0, 0);
      xacc0 = t0; xacc1 = t1;
    }
  };
  computeX(0);
  bool slow = false;                // per-wave sticky fallback (wave-uniform)

  for (int t = 0; t < T_; ++t) {
    // split accumulators: hi-chain (A) and lo-chain (B) -> halved dep chains
    f32x4 accA0 = xacc0, accA1 = xacc1;
    f32x4 accB0 = {0.f, 0.f, 0.f, 0.f}, accB1 = {0.f, 0.f, 0.f, 0.f};

    if (t > 0) {
      const unsigned short* pl = hP + (size_t)(t - 1) * HSTEP + cbase;
      bf16x8 bh[8];
      if (!slow) {
        unsigned need = 0xFFu;      // per-lane granule-pending mask
        int it = 0;
        for (;;) {
          #pragma unroll
          for (int kt = 0; kt < 8; ++kt)
            if (need & (1u << kt)) bh[kt] = load16_sc0(pl + kt * 4096);
          waitv8(bh[0], bh[1], bh[2], bh[3], bh[4], bh[5], bh[6], bh[7]);
          #pragma unroll
          for (int kt = 0; kt < 8; ++kt)
            if (need & (1u << kt)) {
              union { bf16x8 v; unsigned u[4]; } U; U.v = bh[kt];
              if (U.u[0] != SENT && U.u[1] != SENT &&
                  U.u[2] != SENT && U.u[3] != SENT)
                need &= ~(1u << kt);
            }
          if (__all(need == 0u)) break;
          if (++it >= TIMEOUT) { slow = true; break; }   // uniform -> sticky
        }
      }
      if (slow) {                   // proven LLC pair; reload all 8 (idempotent)
        #pragma unroll
        for (int kt = 0; kt < 8; ++kt) {
          const unsigned long long* q = (const unsigned long long*)(pl + kt * 4096);
          for (;;) {
            union { unsigned long long u[2]; bf16x8 v; } U;
            U.u[0] = ldA64(q); U.u[1] = ldA64(q + 1);
            const unsigned w0 = (unsigned)U.u[0], w1 = (unsigned)(U.u[0] >> 32);
            const unsigned w2 = (unsigned)U.u[1], w3 = (unsigned)(U.u[1] >> 32);
            if (w0 != SENT && w1 != SENT && w2 != SENT && w3 != SENT) {
              bh[kt] = U.v; break;
            }
            __builtin_amdgcn_s_sleep(1);
          }
        }
      }
      #pragma unroll
      for (int kt = 0; kt < 8; ++kt) {
        accA0 = MFMA16(ahhi[0][kt], bh[kt], accA0, 0, 0, 0);
        accA1 = MFMA16(ahhi[1][kt], bh[kt], accA1, 0, 0, 0);
        accB0 = MFMA16(ahlo[0][kt], bh[kt], accB0, 0, 0, 0);
        accB1 = MFMA16(ahlo[1][kt], bh[kt], accB1, 0, 0, 0);
      }
    }

    // combine K-split partials across waves via LDS (parity double-buffered:
    // step t writes/reads part[t&1]; the single barrier below separates this
    // step's writes from its reads, and the t+1 barrier separates this step's
    // reads from the t+2 writes to the same buffer).
    #pragma unroll
    for (int r = 0; r < 4; ++r) {
      part[t & 1][wave][r * 68 + lane]       = accA0[r] + accB0[r];
      part[t & 1][wave][(4 + r) * 68 + lane] = accA1[r] + accB1[r];
    }
    __syncthreads();                // the ONLY barrier per step

    // epilogue: 256 threads, 2 rows each; dual-store straight into hP plane t.
    {
      const int n = tid & 15, rp = tid >> 4;
      const int m0 = rp * 2;
      unsigned short o[2];
      #pragma unroll
      for (int rr = 0; rr < 2; ++rr) {
        const int m = m0 + rr;
        const int f = ((m >> 4) * 4 + (m & 3)) * 68 + ((m >> 2) & 3) * 16 + n;
        float s = part[t & 1][0][f] + part[t & 1][1][f]
                + part[t & 1][2][f] + part[t & 1][3][f] + biasS[m];
        o[rr] = f2bf(tanhf(s));
      }
      const unsigned pk = (unsigned)o[0] | ((unsigned)o[1] << 16);
      const int R = r0 + m0;
      unsigned* dst = (unsigned*)(hP + (size_t)t * HSTEP
                      + ((size_t)(R >> 3) * B_ + (b0 + n)) * 8 + (R & 7));
      store32_sc0(dst, pk);         // same-XCD L2 (fast-path visibility)
      stA32(dst, pk);               // write-through LLC (fallback visibility)
      // fire-and-forget: consumers gate on the sentinel, no drain needed
    }

    if (t < T_ - 1) computeX(t + 1);   // independent of h_t
  }
}

// ---- output projection from pack layout: out[b][t][o] ----
__global__ __launch_bounds__(256, 2) void out_proj(
    const unsigned short* __restrict__ hP, const float* __restrict__ WoT,
    const float* __restrict__ b_out, float* __restrict__ out)
{
  const int t = blockIdx.x;
  const int tid = threadIdx.x;
  const int b  = tid & 127;
  const int oh = tid >> 7;                 // wave-uniform output half
  float a0 = b_out[oh * 6 + 0], a1 = b_out[oh * 6 + 1], a2 = b_out[oh * 6 + 2];
  float a3 = b_out[oh * 6 + 3], a4 = b_out[oh * 6 + 4], a5 = b_out[oh * 6 + 5];
  const unsigned short* hp = hP + (size_t)t * HSTEP + (size_t)b * 8;
  const float4* W4 = (const float4*)WoT;
  for (int kb = 0; kb < 128; ++kb) {
    bf16x8 hv = *(const bf16x8*)(hp + (size_t)kb * (B_ * 8));  // 16B coalesced
    #pragma unroll
    for (int j = 0; j < 8; ++j) {
      const int k = kb * 8 + j;
      float h = bf2f((unsigned short)hv[j]);
      float4 wa = W4[k * 4 + oh * 2];       // wave-uniform
      float4 wb = W4[k * 4 + oh * 2 + 1];
      a0 += wa.x * h; a1 += wa.y * h; a2 += wa.z * h;
      a3 += wa.w * h; a4 += wb.x * h; a5 += wb.y * h;
    }
  }
  float* op = out + ((size_t)b * T_ + t) * O_ + oh * 6;
  op[0] = a0; op[1] = a1; op[2] = a2; op[3] = a3; op[4] = a4; op[5] = a5;
}

// ---- host ----
extern "C" void kernel_launch(void* const* d_in, const int* in_sizes, int n_in,
                              void* d_out, int out_size, void* d_ws, size_t ws_size,
                              hipStream_t stream)
{
  const float* x     = (const float*)d_in[0];
  const float* W_ih  = (const float*)d_in[1];
  const float* W_hh  = (const float*)d_in[2];
  const float* b_ih  = (const float*)d_in[3];
  const float* b_hh  = (const float*)d_in[4];
  const float* W_out = (const float*)d_in[5];
  const float* b_out = (const float*)d_in[6];
  float* out = (float*)d_out;

  unsigned short* hP   = (unsigned short*)d_ws;                  // 134.2 MB
  unsigned short* xPhi = hP + (size_t)T_ * HSTEP;                // 8.4 MB
  float*          WoT  = (float*)(xPhi + (size_t)T_ * XSTEP);    // 64 KB

  prep_fill<<<2048, 256, 0, stream>>>(hP);   // sentinel-poison history ring
  prep_xp  <<<T_,   256, 0, stream>>>(x, xPhi);
  prep_misc<<<64,   256, 0, stream>>>(W_out, WoT);
  rnn_mfma <<<256,  256, 0, stream>>>(W_ih, W_hh, b_ih, b_hh, xPhi, hP);
  out_proj <<<T_,   256, 0, stream>>>(hP, WoT, b_out, out);
}

// Round 2
// 3254.813 us; speedup vs baseline: 1.8368x; 1.8368x over previous
//
#include <hip/hip_runtime.h>
#include <hip/hip_bf16.h>

#define B_ 128
#define T_ 512
#define I_ 64
#define H_ 1024
#define O_ 12
#define HSTEP (H_ * B_)   // 131072 bf16 elements per timestep plane of hP
#define XSTEP (I_ * B_)   // 8192 bf16 elements per timestep of xPhi
#define TIMEOUT 2000      // flag-poll passes before sticky per-wave agent fallback
#define RETRYCAP 1024     // post-flag sentinel-retry passes before fallback
#define SENT 0x7FC07FC0u  // bf16 NaN pair: tanh output (finite, |v|<=1) can never produce it

typedef __attribute__((ext_vector_type(8))) short bf16x8;
typedef __attribute__((ext_vector_type(4))) float f32x4;

#define MFMA16 __builtin_amdgcn_mfma_f32_16x16x32_bf16

__device__ __forceinline__ float bf2f(unsigned short s) {
  unsigned u = ((unsigned)s) << 16; float f; __builtin_memcpy(&f, &u, 4); return f;
}
__device__ __forceinline__ unsigned short f2bf(float f) {
  unsigned u; __builtin_memcpy(&u, &f, 4);
  u += 0x7fffu + ((u >> 16) & 1u);   // RNE (finite inputs only here)
  return (unsigned short)(u >> 16);
}

// ---- proven agent-scope (LLC) primitives: slow-path pair ----
__device__ __forceinline__ unsigned long long ldA64(const unsigned long long* p) {
  return __hip_atomic_load(p, __ATOMIC_RELAXED, __HIP_MEMORY_SCOPE_AGENT);
}
__device__ __forceinline__ void stA32(unsigned* p, unsigned v) {
  __hip_atomic_store(p, v, __ATOMIC_RELAXED, __HIP_MEMORY_SCOPE_AGENT);
}

// ---- XCD-local primitives (sc0: bypass L1, served by this XCD's L2): fast pair ----
__device__ __forceinline__ void store32_sc0(unsigned* p, unsigned v) {
  asm volatile("global_store_dword %0, %1, off sc0" :: "v"(p), "v"(v) : "memory");
}
__device__ __forceinline__ unsigned poll_sc0(const unsigned* p) {
  unsigned v;
  asm volatile("global_load_dword %0, %1, off sc0\n\ts_waitcnt vmcnt(0)"
               : "=v"(v) : "v"(p) : "memory");
  return v;
}
__device__ __forceinline__ bf16x8 load16_sc0(const void* p) {
  bf16x8 v;
  asm volatile("global_load_dwordx4 %0, %1, off sc0" : "=v"(v) : "v"(p));
  return v;
}
__device__ __forceinline__ void waitv8(bf16x8& v0, bf16x8& v1, bf16x8& v2, bf16x8& v3,
                                       bf16x8& v4, bf16x8& v5, bf16x8& v6, bf16x8& v7) {
  asm volatile("s_waitcnt vmcnt(0)"
               : "+v"(v0), "+v"(v1), "+v"(v2), "+v"(v3),
                 "+v"(v4), "+v"(v5), "+v"(v6), "+v"(v7) :: "memory");
}

// ---- prep: sentinel-poison the full hP history (data is the correctness gate) ----
__global__ void prep_fill(unsigned short* __restrict__ hP) {
  const size_t stride = (size_t)gridDim.x * 256 * 8;
  size_t idx = ((size_t)blockIdx.x * 256 + threadIdx.x) * 8;
  const short s = (short)0x7FC0;
  bf16x8 v = {s, s, s, s, s, s, s, s};
  const size_t total = (size_t)T_ * HSTEP;
  for (; idx < total; idx += stride) *(bf16x8*)(hP + idx) = v;
}

// ---- prep: x[b][t][i] fp32 -> pack-layout bf16 plane xPhi[t][i/8][b][i%8] ----
__global__ void prep_xp(const float* __restrict__ x,
                        unsigned short* __restrict__ xPhi) {
  const int t = blockIdx.x;
  for (int u = threadIdx.x; u < 1024; u += 256) {   // u = ib*128 + b
    const int ib = u >> 7, b = u & 127;
    const float* src = x + ((size_t)b * T_ + t) * I_ + ib * 8;
    bf16x8 hi;
    #pragma unroll
    for (int j = 0; j < 8; ++j) hi[j] = (short)f2bf(src[j]);
    *(bf16x8*)(xPhi + ((size_t)t * 1024 + u) * 8) = hi;
  }
}

// ---- prep: zero flags + W_out transposed/padded WoT[k][16] ----
// bar: 1024 uints — per-wave flags bar[g*128 + rg*4 + wave] (g<8, rg<32, wave<4)
__global__ void prep_misc(const float* __restrict__ W_out, float* __restrict__ WoT,
                          unsigned* __restrict__ bar) {
  const int idx = blockIdx.x * 256 + threadIdx.x;   // 64 blocks -> 16384 threads
  if (idx < 1024) bar[idx] = 0u;
  const int k = idx >> 4, s = idx & 15;
  float v = 0.0f;
  if (s < 6)                 v = W_out[s * H_ + k];
  else if (s >= 8 && s < 14) v = W_out[(s - 2) * H_ + k];
  WoT[idx] = v;
}

// ---- persistent MFMA recurrence ----
// g = bid&7 (batch group; XCD-pure under round-robin dispatch), rg = bid>>3.
// h exchange: producers dual-store packed bf16 pairs straight into hP plane t
// (sc0 same-XCD L2 + agent LLC insurance), then each producer WAVE posts its
// own flag (t+1, sc0) with NO drain — in-wave program order only. Consumers
// per-wave poll exactly their 32 producer-octet flags (128 B/pass, cheap),
// then bulk-load granules and verify non-sentinel with a short need-mask
// retry (flags can lead data by a few hundred cycles; the sentinel is the
// correctness gate — hP is write-once, so stale reads can only delay).
// One barrier per step (parity double-buffered part[]). Per-wave sticky
// timeout -> agent-scope sentinel spin (proven terminating).
__global__ __launch_bounds__(256, 1) void rnn_mfma(
    const float* __restrict__ W_ih, const float* __restrict__ W_hh,
    const float* __restrict__ b_ih, const float* __restrict__ b_hh,
    const unsigned short* __restrict__ xPhi, unsigned short* __restrict__ hP,
    unsigned* __restrict__ bar)
{
  __shared__ float part[2][4][544];   // [t&1][wave][8 rows x 68 padded]
  __shared__ float biasS[32];
  const int tid = threadIdx.x, bid = blockIdx.x;
  const int wave = tid >> 6, lane = tid & 63, quad = lane >> 4, ln = lane & 15;
  const int g = bid & 7, rg = bid >> 3;
  const int r0 = rg * 32, b0 = g * 16;
  if (tid < 32) biasS[tid] = b_ih[r0 + tid] + b_hh[r0 + tid];

  // A-frags for W_hh (hi/lo split -> fp32-grade W precision), loaded once.
  bf16x8 ahhi[2][8], ahlo[2][8];
  #pragma unroll
  for (int mt = 0; mt < 2; ++mt)
    #pragma unroll
    for (int kt = 0; kt < 8; ++kt) {
      const float* wp = W_hh + (size_t)(r0 + mt * 16 + ln) * H_
                        + wave * 256 + kt * 32 + quad * 8;
      #pragma unroll
      for (int j = 0; j < 8; ++j) {
        float v = wp[j];
        unsigned short h = f2bf(v);
        ahhi[mt][kt][j] = (short)h;
        ahlo[mt][kt][j] = (short)f2bf(v - bf2f(h));
      }
    }
  // A-frags for W_ih: waves 0,1 own the two x K-tiles (i in [32w,32w+32)).
  bf16x8 axhi[2], axlo[2];
  if (wave < 2)
    #pragma unroll
    for (int mt = 0; mt < 2; ++mt) {
      const float* wp = W_ih + (size_t)(r0 + mt * 16 + ln) * I_
                        + wave * 32 + quad * 8;
      #pragma unroll
      for (int j = 0; j < 8; ++j) {
        float v = wp[j];
        unsigned short h = f2bf(v);
        axhi[mt][j] = (short)h;
        axlo[mt][j] = (short)f2bf(v - bf2f(h));
      }
    }
  __syncthreads();

  const int bcol = b0 + ln;
  // Consumer granule base within a plane (shorts). Granule (kt,quad) = octet
  // K8 = wave*32 + kt*4 + quad (rows 8*K8..8*K8+7), batch bcol; produced by
  // block (g, rg=wave*8+kt), producer-wave quad. kt stride = 4*B_*8 = 4096.
  const size_t cbase = ((size_t)(wave * 32 + quad) * B_ + bcol) * 8;
  // This consumer wave's 32 producer-octet flags: bar[g*128 + wave*32 + l].
  const unsigned* fbase = bar + (g << 7) + (wave << 5);

  f32x4 xacc0 = {0.f, 0.f, 0.f, 0.f}, xacc1 = {0.f, 0.f, 0.f, 0.f};
  auto computeX = [&](int t) {      // x-contribution for step t (waves 0,1)
    if (wave < 2) {
      const size_t xo = (((size_t)t * 8 + wave * 4 + quad) * B_ + bcol) * 8;
      bf16x8 bxh = *(const bf16x8*)(xPhi + xo);
      f32x4 t0 = {0.f, 0.f, 0.f, 0.f}, t1 = {0.f, 0.f, 0.f, 0.f};
      t0 = MFMA16(axhi[0], bxh, t0, 0, 0, 0);
      t0 = MFMA16(axlo[0], bxh, t0, 0, 0, 0);
      t1 = MFMA16(axhi[1], bxh, t1, 0, 0, 0);
      t1 = MFMA16(axlo[1], bxh, t1, 0, 0, 0);
      xacc0 = t0; xacc1 = t1;
    }
  };
  computeX(0);
  bool slow = false;                // per-wave sticky fallback (wave-uniform)

  for (int t = 0; t < T_; ++t) {
    // split accumulators: hi-chain (A) and lo-chain (B) -> halved dep chains
    f32x4 accA0 = xacc0, accA1 = xacc1;
    f32x4 accB0 = {0.f, 0.f, 0.f, 0.f}, accB1 = {0.f, 0.f, 0.f, 0.f};

    if (t > 0) {
      const unsigned short* pl = hP + (size_t)(t - 1) * HSTEP + cbase;
      bf16x8 bh[8];
      if (!slow) {
        // 1) cheap per-wave flag gate: 32 lanes x 1 dword per pass
        int ok = 0;
        for (int it = 0; it < TIMEOUT && !ok; ++it) {
          unsigned v = (lane < 32) ? poll_sc0(fbase + lane) : 0xffffffffu;
          ok = __all((int)(v >= (unsigned)t));
        }
        if (!ok) slow = true;
      }
      if (!slow) {
        // 2) bulk load + sentinel verify (flags may lead data slightly)
        unsigned need = 0xFFu;      // per-lane granule-pending mask
        int rt = 0;
        for (;;) {
          #pragma unroll
          for (int kt = 0; kt < 8; ++kt)
            if (need & (1u << kt)) bh[kt] = load16_sc0(pl + kt * 4096);
          waitv8(bh[0], bh[1], bh[2], bh[3], bh[4], bh[5], bh[6], bh[7]);
          #pragma unroll
          for (int kt = 0; kt < 8; ++kt)
            if (need & (1u << kt)) {
              union { bf16x8 v; unsigned u[4]; } U; U.v = bh[kt];
              if (U.u[0] != SENT && U.u[1] != SENT &&
                  U.u[2] != SENT && U.u[3] != SENT)
                need &= ~(1u << kt);
            }
          if (__all(need == 0u)) break;
          if (++rt >= RETRYCAP) { slow = true; break; }  // uniform -> sticky
        }
      }
      if (slow) {                   // proven LLC pair; reload all 8 (idempotent)
        #pragma unroll
        for (int kt = 0; kt < 8; ++kt) {
          const unsigned long long* q = (const unsigned long long*)(pl + kt * 4096);
          for (;;) {
            union { unsigned long long u[2]; bf16x8 v; } U;
            U.u[0] = ldA64(q); U.u[1] = ldA64(q + 1);
            const unsigned w0 = (unsigned)U.u[0], w1 = (unsigned)(U.u[0] >> 32);
            const unsigned w2 = (unsigned)U.u[1], w3 = (unsigned)(U.u[1] >> 32);
            if (w0 != SENT && w1 != SENT && w2 != SENT && w3 != SENT) {
              bh[kt] = U.v; break;
            }
            __builtin_amdgcn_s_sleep(1);
          }
        }
      }
      #pragma unroll
      for (int kt = 0; kt < 8; ++kt) {
        accA0 = MFMA16(ahhi[0][kt], bh[kt], accA0, 0, 0, 0);
        accA1 = MFMA16(ahhi[1][kt], bh[kt], accA1, 0, 0, 0);
        accB0 = MFMA16(ahlo[0][kt], bh[kt], accB0, 0, 0, 0);
        accB1 = MFMA16(ahlo[1][kt], bh[kt], accB1, 0, 0, 0);
      }
    }

    // combine K-split partials across waves via LDS (parity double-buffered:
    // with one barrier per step, buffer reuse at t+2 is fenced by the t+1
    // barrier — write(t)->bar(t)->read(t) ; write(t+1)->bar(t+1) ensures all
    // waves finished read(t) before any wave reaches write(t+2)).
    #pragma unroll
    for (int r = 0; r < 4; ++r) {
      part[t & 1][wave][r * 68 + lane]       = accA0[r] + accB0[r];
      part[t & 1][wave][(4 + r) * 68 + lane] = accA1[r] + accB1[r];
    }
    __syncthreads();                // the ONLY barrier per step

    // epilogue: 256 threads, 2 rows each; dual-store into hP plane t, then
    // each wave posts its own flag (covers exactly its 8 rows = 1 octet/rg).
    {
      const int n = tid & 15, rp = tid >> 4;
      const int m0 = rp * 2;
      unsigned short o[2];
      #pragma unroll
      for (int rr = 0; rr < 2; ++rr) {
        const int m = m0 + rr;
        const int f = ((m >> 4) * 4 + (m & 3)) * 68 + ((m >> 2) & 3) * 16 + n;
        float s = part[t & 1][0][f] + part[t & 1][1][f]
                + part[t & 1][2][f] + part[t & 1][3][f] + biasS[m];
        o[rr] = f2bf(tanhf(s));
      }
      const unsigned pk = (unsigned)o[0] | ((unsigned)o[1] << 16);
      const int R = r0 + m0;
      unsigned* dst = (unsigned*)(hP + (size_t)t * HSTEP
                      + ((size_t)(R >> 3) * B_ + (b0 + n)) * 8 + (R & 7));
      store32_sc0(dst, pk);         // same-XCD L2 (fast-path visibility)
      stA32(dst, pk);               // LLC insurance (fallback visibility)
      // per-wave flag: in-wave program order after this wave's data stores;
      // no drain — consumers sentinel-verify, so early flags only cost retries
      if ((tid & 63) == 0)
        store32_sc0((unsigned*)(bar + (g << 7) + (rg << 2) + wave),
                    (unsigned)(t + 1));
    }

    if (t < T_ - 1) computeX(t + 1);   // independent of h_t
  }
}

// ---- output projection from pack layout: out[b][t][o] ----
__global__ __launch_bounds__(256, 2) void out_proj(
    const unsigned short* __restrict__ hP, const float* __restrict__ WoT,
    const float* __restrict__ b_out, float* __restrict__ out)
{
  const int t = blockIdx.x;
  const int tid = threadIdx.x;
  const int b  = tid & 127;
  const int oh = tid >> 7;                 // wave-uniform output half
  float a0 = b_out[oh * 6 + 0], a1 = b_out[oh * 6 + 1], a2 = b_out[oh * 6 + 2];
  float a3 = b_out[oh * 6 + 3], a4 = b_out[oh * 6 + 4], a5 = b_out[oh * 6 + 5];
  const unsigned short* hp = hP + (size_t)t * HSTEP + (size_t)b * 8;
  const float4* W4 = (const float4*)WoT;
  for (int kb = 0; kb < 128; ++kb) {
    bf16x8 hv = *(const bf16x8*)(hp + (size_t)kb * (B_ * 8));  // 16B coalesced
    #pragma unroll
    for (int j = 0; j < 8; ++j) {
      const int k = kb * 8 + j;
      float h = bf2f((unsigned short)hv[j]);
      float4 wa = W4[k * 4 + oh * 2];       // wave-uniform
      float4 wb = W4[k * 4 + oh * 2 + 1];
      a0 += wa.x * h; a1 += wa.y * h; a2 += wa.z * h;
      a3 += wa.w * h; a4 += wb.x * h; a5 += wb.y * h;
    }
  }
  float* op = out + ((size_t)b * T_ + t) * O_ + oh * 6;
  op[0] = a0; op[1] = a1; op[2] = a2; op[3] = a3; op[4] = a4; op[5] = a5;
}

// ---- host ----
extern "C" void kernel_launch(void* const* d_in, const int* in_sizes, int n_in,
                              void* d_out, int out_size, void* d_ws, size_t ws_size,
                              hipStream_t stream)
{
  const float* x     = (const float*)d_in[0];
  const float* W_ih  = (const float*)d_in[1];
  const float* W_hh  = (const float*)d_in[2];
  const float* b_ih  = (const float*)d_in[3];
  const float* b_hh  = (const float*)d_in[4];
  const float* W_out = (const float*)d_in[5];
  const float* b_out = (const float*)d_in[6];
  float* out = (float*)d_out;

  unsigned short* hP   = (unsigned short*)d_ws;                  // 134.2 MB
  unsigned short* xPhi = hP + (size_t)T_ * HSTEP;                // 8.4 MB
  float*          WoT  = (float*)(xPhi + (size_t)T_ * XSTEP);    // 64 KB
  unsigned*       bar  = (unsigned*)(WoT + (size_t)H_ * 16);     // 4 KB

  prep_fill<<<2048, 256, 0, stream>>>(hP);   // sentinel-poison history ring
  prep_xp  <<<T_,   256, 0, stream>>>(x, xPhi);
  prep_misc<<<64,   256, 0, stream>>>(W_out, WoT, bar);
  rnn_mfma <<<256,  256, 0, stream>>>(W_ih, W_hh, b_ih, b_hh, xPhi, hP, bar);
  out_proj <<<T_,   256, 0, stream>>>(hP, WoT, b_out, out);
}

// Round 3
// 2713.302 us; speedup vs baseline: 2.2034x; 1.1996x over previous
//
#include <hip/hip_runtime.h>
#include <hip/hip_bf16.h>

#define B_ 128
#define T_ 512
#define I_ 64
#define H_ 1024
#define O_ 12
#define HSTEP (H_ * B_)   // 131072 bf16 elements per timestep plane of hP
#define XSTEP (I_ * B_)   // 8192 bf16 elements per timestep of xPhi
#define RSLOT 16384       // shorts per ring slot: 128 octets * 16 batches * 8
#define TIMEOUT 2000      // fast-flag poll rounds before sticky sentinel fallback
#define SENT 0x7FC07FC0u  // bf16 NaN pair: tanh output (finite) never produces it

typedef __attribute__((ext_vector_type(8))) short bf16x8;
typedef __attribute__((ext_vector_type(4))) float f32x4;

#define MFMA16 __builtin_amdgcn_mfma_f32_16x16x32_bf16

__device__ __forceinline__ float bf2f(unsigned short s) {
  unsigned u = ((unsigned)s) << 16; float f; __builtin_memcpy(&f, &u, 4); return f;
}
__device__ __forceinline__ unsigned short f2bf(float f) {
  unsigned u; __builtin_memcpy(&u, &f, 4);
  u += 0x7fffu + ((u >> 16) & 1u);   // RNE (finite inputs only here)
  return (unsigned short)(u >> 16);
}

// ---- proven agent-scope (LLC) primitives: slow-path pair ----
__device__ __forceinline__ unsigned long long ldA64(const unsigned long long* p) {
  return __hip_atomic_load(p, __ATOMIC_RELAXED, __HIP_MEMORY_SCOPE_AGENT);
}
__device__ __forceinline__ void stA32(unsigned* p, unsigned v) {
  __hip_atomic_store(p, v, __ATOMIC_RELAXED, __HIP_MEMORY_SCOPE_AGENT);
}

// ---- XCD-local primitives (sc0: bypass L1, served by this XCD's L2) ----
__device__ __forceinline__ void store32_sc0(unsigned* p, unsigned v) {
  asm volatile("global_store_dword %0, %1, off sc0" :: "v"(p), "v"(v) : "memory");
}
__device__ __forceinline__ unsigned poll_sc0(const unsigned* p) {
  unsigned v;
  asm volatile("global_load_dword %0, %1, off sc0\n\ts_waitcnt vmcnt(0)"
               : "=v"(v) : "v"(p) : "memory");
  return v;
}
__device__ __forceinline__ bf16x8 load16_sc0(const void* p) {
  bf16x8 v;
  asm volatile("global_load_dwordx4 %0, %1, off sc0" : "=v"(v) : "v"(p));
  return v;
}
__device__ __forceinline__ void waitv8(bf16x8& v0, bf16x8& v1, bf16x8& v2, bf16x8& v3,
                                       bf16x8& v4, bf16x8& v5, bf16x8& v6, bf16x8& v7) {
  asm volatile("s_waitcnt vmcnt(0)"
               : "+v"(v0), "+v"(v1), "+v"(v2), "+v"(v3),
                 "+v"(v4), "+v"(v5), "+v"(v6), "+v"(v7) :: "memory");
}

// ---- prep: sentinel-poison hP (slow-path correctness gate; fast path never reads it) ----
__global__ void prep_fill(unsigned short* __restrict__ hP) {
  const size_t stride = (size_t)gridDim.x * 256 * 8;
  size_t idx = ((size_t)blockIdx.x * 256 + threadIdx.x) * 8;
  const short s = (short)0x7FC0;
  bf16x8 v = {s, s, s, s, s, s, s, s};
  const size_t total = (size_t)T_ * HSTEP;
  for (; idx < total; idx += stride) *(bf16x8*)(hP + idx) = v;
}

// ---- prep: x[b][t][i] fp32 -> pack-layout bf16 plane xPhi[t][i/8][b][i%8] ----
__global__ void prep_xp(const float* __restrict__ x,
                        unsigned short* __restrict__ xPhi) {
  const int t = blockIdx.x;
  for (int u = threadIdx.x; u < 1024; u += 256) {   // u = ib*128 + b
    const int ib = u >> 7, b = u & 127;
    const float* src = x + ((size_t)b * T_ + t) * I_ + ib * 8;
    bf16x8 hi;
    #pragma unroll
    for (int j = 0; j < 8; ++j) hi[j] = (short)f2bf(src[j]);
    *(bf16x8*)(xPhi + ((size_t)t * 1024 + u) * 8) = hi;
  }
}

// ---- prep: zero flags + W_out transposed/padded WoT[k][16] ----
// bar uints: [0..255] fast flags bar[g*32+rg] (one 128B line per g).
__global__ void prep_misc(const float* __restrict__ W_out, float* __restrict__ WoT,
                          unsigned* __restrict__ bar) {
  const int idx = blockIdx.x * 256 + threadIdx.x;   // 64 blocks -> 16384 threads
  if (idx < 1024) bar[idx] = 0u;
  const int k = idx >> 4, s = idx & 15;
  float v = 0.0f;
  if (s < 6)                 v = W_out[s * H_ + k];
  else if (s >= 8 && s < 14) v = W_out[(s - 2) * H_ + k];
  WoT[idx] = v;
}

// ---- persistent MFMA recurrence ----
// Round-0 proven skeleton: sc0 ring rF + block flags + single poller wave +
// 3 barriers + sticky block mode. Surgical changes vs round 0:
//  (1) drain before flag post covers ONLY sc0 L2 stores (rF + hP); the LLC
//      insurance is one stA32 per thread to hP, issued AFTER the flag,
//      fire-and-forget (its consumers sentinel-gate, so no drain ever).
//  (2) poller is wave 3, which issues NO stA32/xPhi loads -> poll_sc0's
//      internal vmcnt(0) never waits on an LLC ack. Wave 2 covers wave 3's
//      insurance dwords via LDS-shared pk.
//  (3) computeX(t+1) moved after the flag post (out of the drain).
// Slow path (sticky, on poll timeout): agent-scope sentinel spin on poisoned
// hP (proven terminating in rounds 1-2); producers always dual-publish.
__global__ __launch_bounds__(256, 1) void rnn_mfma(
    const float* __restrict__ W_ih, const float* __restrict__ W_hh,
    const float* __restrict__ b_ih, const float* __restrict__ b_hh,
    const unsigned short* __restrict__ xPhi, unsigned short* __restrict__ hP,
    unsigned short* __restrict__ rF, unsigned* __restrict__ bar)
{
  __shared__ float part[4][544];    // 8 rows x 68 (padded: conflict-free)
  __shared__ float biasS[32];
  __shared__ unsigned pkS[256];     // packed outputs (for wave2->wave3 insurance)
  __shared__ unsigned modeS;        // 1 = fast, one-way latch to 0
  const int tid = threadIdx.x, bid = blockIdx.x;
  const int wave = tid >> 6, lane = tid & 63, quad = lane >> 4, ln = lane & 15;
  const int g = bid & 7, rg = bid >> 3;
  const int r0 = rg * 32, b0 = g * 16;
  if (tid < 32) biasS[tid] = b_ih[r0 + tid] + b_hh[r0 + tid];
  if (tid == 0) modeS = 1u;

  // A-frags for W_hh (hi/lo split -> fp32-grade W precision), loaded once.
  bf16x8 ahhi[2][8], ahlo[2][8];
  #pragma unroll
  for (int mt = 0; mt < 2; ++mt)
    #pragma unroll
    for (int kt = 0; kt < 8; ++kt) {
      const float* wp = W_hh + (size_t)(r0 + mt * 16 + ln) * H_
                        + wave * 256 + kt * 32 + quad * 8;
      #pragma unroll
      for (int j = 0; j < 8; ++j) {
        float v = wp[j];
        unsigned short h = f2bf(v);
        ahhi[mt][kt][j] = (short)h;
        ahlo[mt][kt][j] = (short)f2bf(v - bf2f(h));
      }
    }
  // A-frags for W_ih: waves 0,1 own the two x K-tiles (i in [32w,32w+32)).
  bf16x8 axhi[2], axlo[2];
  if (wave < 2)
    #pragma unroll
    for (int mt = 0; mt < 2; ++mt) {
      const float* wp = W_ih + (size_t)(r0 + mt * 16 + ln) * I_
                        + wave * 32 + quad * 8;
      #pragma unroll
      for (int j = 0; j < 8; ++j) {
        float v = wp[j];
        unsigned short h = f2bf(v);
        axhi[mt][j] = (short)h;
        axlo[mt][j] = (short)f2bf(v - bf2f(h));
      }
    }
  __syncthreads();
  unsigned mode = 1u;               // block-uniform; updated only at barriers

  const int bcol = b0 + ln;
  unsigned short* rFg = rF + (size_t)g * 2 * RSLOT;
  // Slow-path granule base in a full hP plane (shorts): octet K8 = wave*32 +
  // kt*4 + quad, batch bcol; kt stride = 4 octets * B_ * 8 = 4096 shorts.
  const size_t cbase = ((size_t)(wave * 32 + quad) * B_ + bcol) * 8;

  f32x4 xacc0 = {0.f, 0.f, 0.f, 0.f}, xacc1 = {0.f, 0.f, 0.f, 0.f};
  auto computeX = [&](int t) {      // x-contribution for step t (waves 0,1)
    if (wave < 2) {
      const size_t xo = (((size_t)t * 8 + wave * 4 + quad) * B_ + bcol) * 8;
      bf16x8 bxh = *(const bf16x8*)(xPhi + xo);
      f32x4 t0 = {0.f, 0.f, 0.f, 0.f}, t1 = {0.f, 0.f, 0.f, 0.f};
      t0 = MFMA16(axhi[0], bxh, t0, 0, 0, 0);
      t0 = MFMA16(axlo[0], bxh, t0, 0, 0, 0);
      t1 = MFMA16(axhi[1], bxh, t1, 0, 0, 0);
      t1 = MFMA16(axlo[1], bxh, t1, 0, 0, 0);
      xacc0 = t0; xacc1 = t1;
    }
  };
  computeX(0);

  for (int t = 0; t < T_; ++t) {
    // split accumulators: hi-chain (A) and lo-chain (B) -> halved dep chains
    f32x4 accA0 = xacc0, accA1 = xacc1;
    f32x4 accB0 = {0.f, 0.f, 0.f, 0.f}, accB1 = {0.f, 0.f, 0.f, 0.f};

    if (t > 0) {
      bf16x8 bh[8];
      if (mode) {
        // fast: guaranteed-visible (post-drain flags) -> single pass, no checks
        const int soff = ((wave * 32 + quad) * 16 + ln) * 8;   // shorts
        const unsigned short* slot = rFg + ((t - 1) & 1) * RSLOT + soff;
        #pragma unroll
        for (int kt = 0; kt < 8; ++kt)
          bh[kt] = load16_sc0(slot + kt * 512);                // XCD-L2 hits
        waitv8(bh[0], bh[1], bh[2], bh[3], bh[4], bh[5], bh[6], bh[7]);
      } else {
        // slow: agent-scope sentinel spin on poisoned hP (proven r1/r2)
        const unsigned short* pl = hP + (size_t)(t - 1) * HSTEP + cbase;
        #pragma unroll
        for (int kt = 0; kt < 8; ++kt) {
          const unsigned long long* q = (const unsigned long long*)(pl + kt * 4096);
          for (;;) {
            union { unsigned long long u[2]; bf16x8 v; } U;
            U.u[0] = ldA64(q); U.u[1] = ldA64(q + 1);
            const unsigned w0 = (unsigned)U.u[0], w1 = (unsigned)(U.u[0] >> 32);
            const unsigned w2 = (unsigned)U.u[1], w3 = (unsigned)(U.u[1] >> 32);
            if (w0 != SENT && w1 != SENT && w2 != SENT && w3 != SENT) {
              bh[kt] = U.v; break;
            }
            __builtin_amdgcn_s_sleep(1);
          }
        }
      }
      #pragma unroll
      for (int kt = 0; kt < 8; ++kt) {
        accA0 = MFMA16(ahhi[0][kt], bh[kt], accA0, 0, 0, 0);
        accA1 = MFMA16(ahhi[1][kt], bh[kt], accA1, 0, 0, 0);
        accB0 = MFMA16(ahlo[0][kt], bh[kt], accB0, 0, 0, 0);
        accB1 = MFMA16(ahlo[1][kt], bh[kt], accB1, 0, 0, 0);
      }
    }

    // combine K-split partials across waves via LDS (rows padded to 68)
    #pragma unroll
    for (int r = 0; r < 4; ++r) {
      part[wave][r * 68 + lane]       = accA0[r] + accB0[r];
      part[wave][(4 + r) * 68 + lane] = accA1[r] + accB1[r];
    }
    __syncthreads();                                           // barrier #1

    // epilogue: 256 threads, 2 rows each; sc0 publish to ring + hP plane t
    unsigned pk; unsigned* hPdst;
    {
      const int n = tid & 15, rp = tid >> 4;
      const int m0 = rp * 2;
      unsigned short o[2];
      #pragma unroll
      for (int rr = 0; rr < 2; ++rr) {
        const int m = m0 + rr;
        const int f = ((m >> 4) * 4 + (m & 3)) * 68 + ((m >> 2) & 3) * 16 + n;
        float s = part[0][f] + part[1][f] + part[2][f] + part[3][f] + biasS[m];
        o[rr] = f2bf(tanhf(s));
      }
      pk = (unsigned)o[0] | ((unsigned)o[1] << 16);
      const int R = r0 + m0;
      hPdst = (unsigned*)(hP + (size_t)t * HSTEP
                          + ((size_t)(R >> 3) * B_ + (b0 + n)) * 8 + (R & 7));
      store32_sc0((unsigned*)(rFg + (t & 1) * RSLOT
                              + ((R >> 3) * 16 + n) * 8 + (R & 7)), pk);
      store32_sc0(hPdst, pk);
      pkS[tid] = pk;                 // share for wave2's peer insurance
    }

    if (t < T_ - 1) {
      asm volatile("s_waitcnt vmcnt(0)" ::: "memory");  // sc0 L2 acks only (fast)
      __syncthreads();                                  // barrier #2
      if (tid == 0) store32_sc0(&bar[g * 32 + rg], (unsigned)(t + 1));

      // LLC insurance AFTER the flag, fire-and-forget (consumers sentinel-gate).
      // Wave 3 stays store-free so its poll passes never wait an LLC ack.
      if (wave == 2) {
        const int p = tid + 64;                         // wave-3 peer
        const int pn = p & 15, pm0 = (p >> 4) * 2;
        const int PR = r0 + pm0;
        unsigned* pdst = (unsigned*)(hP + (size_t)t * HSTEP
                         + ((size_t)(PR >> 3) * B_ + (b0 + pn)) * 8 + (PR & 7));
        stA32(pdst, pkS[p]);
      }
      if (wave < 3) stA32(hPdst, pk);

      computeX(t + 1);                                  // waves 0,1; overlaps poll

      if (wave == 3 && mode) {                          // clean-queue poller
        int ok = 0;
        for (int it = 0; it < TIMEOUT && !ok; ++it) {
          unsigned v = (lane < 32) ? poll_sc0(&bar[g * 32 + lane]) : 0xffffffffu;
          ok = __all((int)(v >= (unsigned)(t + 1)));
        }
        if (!ok && lane == 0) modeS = 0u;   // sticky fallback to sentinel path
      }
      __syncthreads();                                  // barrier #3
      mode = modeS;                 // block-uniform mode for next step's loads
    }
  }
}

// ---- output projection from pack layout: out[b][t][o] ----
__global__ __launch_bounds__(256, 2) void out_proj(
    const unsigned short* __restrict__ hP, const float* __restrict__ WoT,
    const float* __restrict__ b_out, float* __restrict__ out)
{
  const int t = blockIdx.x;
  const int tid = threadIdx.x;
  const int b  = tid & 127;
  const int oh = tid >> 7;                 // wave-uniform output half
  float a0 = b_out[oh * 6 + 0], a1 = b_out[oh * 6 + 1], a2 = b_out[oh * 6 + 2];
  float a3 = b_out[oh * 6 + 3], a4 = b_out[oh * 6 + 4], a5 = b_out[oh * 6 + 5];
  const unsigned short* hp = hP + (size_t)t * HSTEP + (size_t)b * 8;
  const float4* W4 = (const float4*)WoT;
  for (int kb = 0; kb < 128; ++kb) {
    bf16x8 hv = *(const bf16x8*)(hp + (size_t)kb * (B_ * 8));  // 16B coalesced
    #pragma unroll
    for (int j = 0; j < 8; ++j) {
      const int k = kb * 8 + j;
      float h = bf2f((unsigned short)hv[j]);
      float4 wa = W4[k * 4 + oh * 2];       // wave-uniform
      float4 wb = W4[k * 4 + oh * 2 + 1];
      a0 += wa.x * h; a1 += wa.y * h; a2 += wa.z * h;
      a3 += wa.w * h; a4 += wb.x * h; a5 += wb.y * h;
    }
  }
  float* op = out + ((size_t)b * T_ + t) * O_ + oh * 6;
  op[0] = a0; op[1] = a1; op[2] = a2; op[3] = a3; op[4] = a4; op[5] = a5;
}

// ---- host ----
extern "C" void kernel_launch(void* const* d_in, const int* in_sizes, int n_in,
                              void* d_out, int out_size, void* d_ws, size_t ws_size,
                              hipStream_t stream)
{
  const float* x     = (const float*)d_in[0];
  const float* W_ih  = (const float*)d_in[1];
  const float* W_hh  = (const float*)d_in[2];
  const float* b_ih  = (const float*)d_in[3];
  const float* b_hh  = (const float*)d_in[4];
  const float* W_out = (const float*)d_in[5];
  const float* b_out = (const float*)d_in[6];
  float* out = (float*)d_out;

  unsigned short* hP   = (unsigned short*)d_ws;                  // 134.2 MB
  unsigned short* xPhi = hP + (size_t)T_ * HSTEP;                // 8.4 MB
  float*          WoT  = (float*)(xPhi + (size_t)T_ * XSTEP);    // 64 KB
  unsigned short* rF   = (unsigned short*)(WoT + (size_t)H_ * 16); // 512 KB
  unsigned*       bar  = (unsigned*)(rF + (size_t)8 * 2 * RSLOT);  // 4 KB

  prep_fill<<<2048, 256, 0, stream>>>(hP);   // sentinel-poison (slow-path gate)
  prep_xp  <<<T_,   256, 0, stream>>>(x, xPhi);
  prep_misc<<<64,   256, 0, stream>>>(W_out, WoT, bar);
  rnn_mfma <<<256,  256, 0, stream>>>(W_ih, W_hh, b_ih, b_hh, xPhi, hP, rF, bar);
  out_proj <<<T_,   256, 0, stream>>>(hP, WoT, b_out, out);
}

// Round 5
// 1937.161 us; speedup vs baseline: 3.0862x; 1.4007x over previous
//
#include <hip/hip_runtime.h>
#include <hip/hip_bf16.h>

#define B_ 128
#define T_ 512
#define I_ 64
#define H_ 1024
#define O_ 12
#define HSTEP (H_ * B_)   // 131072 bf16 elements per timestep of hP
#define XSTEP (I_ * B_)   // 8192 bf16 elements per timestep of xPhi
#define RSLOT 16384       // shorts per ring slot: 128 kb * 16 batches * 8
#define TIMEOUT 2000      // fast-flag poll rounds before sticky fallback
#define FSTRIDE 32        // uints between flags: one 128-B L2 line per flag
#define SLOWOFF 8192      // uint offset of slow-flag region in bar

typedef __attribute__((ext_vector_type(8))) short bf16x8;
typedef __attribute__((ext_vector_type(4))) float f32x4;

#define MFMA16 __builtin_amdgcn_mfma_f32_16x16x32_bf16

__device__ __forceinline__ float bf2f(unsigned short s) {
  unsigned u = ((unsigned)s) << 16; float f; __builtin_memcpy(&f, &u, 4); return f;
}
__device__ __forceinline__ unsigned short f2bf(float f) {
  unsigned u; __builtin_memcpy(&u, &f, 4);
  u += 0x7fffu + ((u >> 16) & 1u);   // RNE (finite inputs only here)
  return (unsigned short)(u >> 16);
}

// ---- proven agent-scope (LLC) atomics ----
__device__ __forceinline__ unsigned ldA32(const unsigned* p) {
  return __hip_atomic_load(p, __ATOMIC_RELAXED, __HIP_MEMORY_SCOPE_AGENT);
}
__device__ __forceinline__ void stA32(unsigned* p, unsigned v) {
  __hip_atomic_store(p, v, __ATOMIC_RELAXED, __HIP_MEMORY_SCOPE_AGENT);
}
__device__ __forceinline__ unsigned long long ldA64(const unsigned long long* p) {
  return __hip_atomic_load(p, __ATOMIC_RELAXED, __HIP_MEMORY_SCOPE_AGENT);
}

// ---- XCD-local primitives (sc0: bypass L1, served by this XCD's L2) ----
// Speed-only: every use has a proven-slow dual. Never load-bearing for
// correctness or termination.
__device__ __forceinline__ void store32_sc0(unsigned* p, unsigned v) {
  asm volatile("global_store_dword %0, %1, off sc0" :: "v"(p), "v"(v) : "memory");
}
__device__ __forceinline__ unsigned poll_sc0(const unsigned* p) {
  unsigned v;
  asm volatile("global_load_dword %0, %1, off sc0\n\ts_waitcnt vmcnt(0)"
               : "=v"(v) : "v"(p) : "memory");
  return v;
}
__device__ __forceinline__ bf16x8 load16_sc0(const void* p) {
  bf16x8 v;
  asm volatile("global_load_dwordx4 %0, %1, off sc0" : "=v"(v) : "v"(p));
  return v;
}
__device__ __forceinline__ void waitv8(bf16x8& v0, bf16x8& v1, bf16x8& v2, bf16x8& v3,
                                       bf16x8& v4, bf16x8& v5, bf16x8& v6, bf16x8& v7) {
  asm volatile("s_waitcnt vmcnt(0)"
               : "+v"(v0), "+v"(v1), "+v"(v2), "+v"(v3),
                 "+v"(v4), "+v"(v5), "+v"(v6), "+v"(v7) :: "memory");
}

// ---- prep: x[b][t][i] fp32 -> pack-layout bf16 plane xPhi[t][i/8][b][i%8] ----
__global__ void prep_xp(const float* __restrict__ x,
                        unsigned short* __restrict__ xPhi) {
  const int t = blockIdx.x;
  for (int u = threadIdx.x; u < 1024; u += 256) {   // u = ib*128 + b
    const int ib = u >> 7, b = u & 127;
    const float* src = x + ((size_t)b * T_ + t) * I_ + ib * 8;
    bf16x8 hi;
    #pragma unroll
    for (int j = 0; j < 8; ++j) hi[j] = (short)f2bf(src[j]);
    *(bf16x8*)(xPhi + ((size_t)t * 1024 + u) * 8) = hi;
  }
}

// ---- prep: zero flags + W_out transposed/padded WoT[k][16] ----
// bar: 16384 uints. fast flag (g,rg) at bar[(g*32+rg)*FSTRIDE] — one 128-B
// line per flag (kills the r0 single-line hotspot: 32 stores + 1024 poll
// reads per step previously serialized on ONE L2 line). slow flags at
// bar[SLOWOFF + (g*32+rg)*FSTRIDE], same spreading.
__global__ void prep_misc(const float* __restrict__ W_out, float* __restrict__ WoT,
                          unsigned* __restrict__ bar) {
  const int idx = blockIdx.x * 256 + threadIdx.x;   // 64 blocks -> 16384 threads
  bar[idx] = 0u;                                    // covers both flag regions
  const int k = idx >> 4, s = idx & 15;
  float v = 0.0f;
  if (s < 6)                 v = W_out[s * H_ + k];
  else if (s >= 8 && s < 14) v = W_out[(s - 2) * H_ + k];
  WoT[idx] = v;
}

// ---- persistent MFMA recurrence ----
// EXACT round-0 skeleton (empirically best of 4 protocol variants): 2-deep
// rings rF (sc0, XCD-L2) + rS (LLC, proven), dual-publish + dual flags,
// post-drain flag post, single poller wave, 3 barriers, sticky block mode.
// Single change this round: flags are padded to one 128-B line each.
__global__ __launch_bounds__(256, 1) void rnn_mfma(
    const float* __restrict__ W_ih, const float* __restrict__ W_hh,
    const float* __restrict__ b_ih, const float* __restrict__ b_hh,
    const unsigned short* __restrict__ xPhi, unsigned short* __restrict__ hP,
    unsigned short* __restrict__ rF, unsigned short* __restrict__ rS,
    unsigned* __restrict__ bar)
{
  __shared__ float part[4][544];    // 8 rows x 68 (padded: conflict-free)
  __shared__ float biasS[32];
  __shared__ unsigned modeS;        // 1 = fast, one-way latch to 0
  const int tid = threadIdx.x, bid = blockIdx.x;
  const int wave = tid >> 6, lane = tid & 63, quad = lane >> 4, ln = lane & 15;
  const int g = bid & 7, rg = bid >> 3;
  const int r0 = rg * 32, b0 = g * 16;
  if (tid < 32) biasS[tid] = b_ih[r0 + tid] + b_hh[r0 + tid];
  if (tid == 0) modeS = 1u;

  // A-frags for W_hh (hi/lo split -> fp32-grade W precision), loaded once.
  bf16x8 ahhi[2][8], ahlo[2][8];
  #pragma unroll
  for (int mt = 0; mt < 2; ++mt)
    #pragma unroll
    for (int kt = 0; kt < 8; ++kt) {
      const float* wp = W_hh + (size_t)(r0 + mt * 16 + ln) * H_
                        + wave * 256 + kt * 32 + quad * 8;
      #pragma unroll
      for (int j = 0; j < 8; ++j) {
        float v = wp[j];
        unsigned short h = f2bf(v);
        ahhi[mt][kt][j] = (short)h;
        ahlo[mt][kt][j] = (short)f2bf(v - bf2f(h));
      }
    }
  // A-frags for W_ih: waves 0,1 own the two x K-tiles (i in [32w,32w+32)).
  bf16x8 axhi[2], axlo[2];
  if (wave < 2)
    #pragma unroll
    for (int mt = 0; mt < 2; ++mt) {
      const float* wp = W_ih + (size_t)(r0 + mt * 16 + ln) * I_
                        + wave * 32 + quad * 8;
      #pragma unroll
      for (int j = 0; j < 8; ++j) {
        float v = wp[j];
        unsigned short h = f2bf(v);
        axhi[mt][j] = (short)h;
        axlo[mt][j] = (short)f2bf(v - bf2f(h));
      }
    }
  __syncthreads();
  unsigned mode = 1u;               // block-uniform; updated only at barriers

  const int bcol = b0 + ln;
  unsigned short* rFg = rF + (size_t)g * 2 * RSLOT;
  unsigned short* rSg = rS + (size_t)g * 2 * RSLOT;

  f32x4 xacc0 = {0.f, 0.f, 0.f, 0.f}, xacc1 = {0.f, 0.f, 0.f, 0.f};
  auto computeX = [&](int t) {      // x-contribution for step t (waves 0,1)
    if (wave < 2) {
      const size_t xo = (((size_t)t * 8 + wave * 4 + quad) * B_ + bcol) * 8;
      bf16x8 bxh = *(const bf16x8*)(xPhi + xo);
      f32x4 t0 = {0.f, 0.f, 0.f, 0.f}, t1 = {0.f, 0.f, 0.f, 0.f};
      t0 = MFMA16(axhi[0], bxh, t0, 0, 0, 0);
      t0 = MFMA16(axlo[0], bxh, t0, 0, 0, 0);
      t1 = MFMA16(axhi[1], bxh, t1, 0, 0, 0);
      t1 = MFMA16(axlo[1], bxh, t1, 0, 0, 0);
      xacc0 = t0; xacc1 = t1;
    }
  };
  computeX(0);

  for (int t = 0; t < T_; ++t) {
    // split accumulators: hi-chain (A) and lo-chain (B) -> halved dep chains
    f32x4 accA0 = xacc0, accA1 = xacc1;
    f32x4 accB0 = {0.f, 0.f, 0.f, 0.f}, accB1 = {0.f, 0.f, 0.f, 0.f};

    if (t > 0) {
      const int soff = ((wave * 32 + quad) * 16 + ln) * 8;   // shorts
      bf16x8 bh[8];
      if (mode) {
        const unsigned short* slot = rFg + ((t - 1) & 1) * RSLOT + soff;
        #pragma unroll
        for (int kt = 0; kt < 8; ++kt)
          bh[kt] = load16_sc0(slot + kt * 512);              // XCD-L2 hits
        waitv8(bh[0], bh[1], bh[2], bh[3], bh[4], bh[5], bh[6], bh[7]);
      } else {
        const unsigned long long* slot =
            (const unsigned long long*)(rSg + ((t - 1) & 1) * RSLOT + soff);
        #pragma unroll
        for (int kt = 0; kt < 8; ++kt) {
          union { unsigned long long u[2]; bf16x8 v; } U;
          U.u[0] = ldA64(slot + kt * 128);
          U.u[1] = ldA64(slot + kt * 128 + 1);
          bh[kt] = U.v;
        }
      }
      #pragma unroll
      for (int kt = 0; kt < 8; ++kt) {
        accA0 = MFMA16(ahhi[0][kt], bh[kt], accA0, 0, 0, 0);
        accA1 = MFMA16(ahhi[1][kt], bh[kt], accA1, 0, 0, 0);
        accB0 = MFMA16(ahlo[0][kt], bh[kt], accB0, 0, 0, 0);
        accB1 = MFMA16(ahlo[1][kt], bh[kt], accB1, 0, 0, 0);
      }
    }

    // combine K-split partials across waves via LDS (rows padded to 68)
    #pragma unroll
    for (int r = 0; r < 4; ++r) {
      part[wave][r * 68 + lane]       = accA0[r] + accB0[r];
      part[wave][(4 + r) * 68 + lane] = accA1[r] + accB1[r];
    }
    __syncthreads();

    // epilogue: 256 threads, 2 rows each; dual-publish rings + history store
    {
      const int n = tid & 15, rp = tid >> 4;
      const int m0 = rp * 2;
      unsigned short o[2];
      #pragma unroll
      for (int rr = 0; rr < 2; ++rr) {
        const int m = m0 + rr;
        const int f = ((m >> 4) * 4 + (m & 3)) * 68 + ((m >> 2) & 3) * 16 + n;
        float s = part[0][f] + part[1][f] + part[2][f] + part[3][f] + biasS[m];
        o[rr] = f2bf(tanhf(s));
      }
      const unsigned pk = (unsigned)o[0] | ((unsigned)o[1] << 16);
      const int R = r0 + m0;
      // history (plain cached write-back; consumed only by out_proj)
      *(unsigned*)(hP + (size_t)t * HSTEP
                   + ((size_t)(R >> 3) * B_ + (b0 + n)) * 8 + (R & 7)) = pk;
      // rings (group-local batch index n)
      const int soff = ((R >> 3) * 16 + n) * 8 + (R & 7);
      store32_sc0((unsigned*)(rFg + (t & 1) * RSLOT + soff), pk);
      stA32      ((unsigned*)(rSg + (t & 1) * RSLOT + soff), pk);
    }

    if (t < T_ - 1) {
      computeX(t + 1);                                   // independent of h_t
      asm volatile("s_waitcnt vmcnt(0)" ::: "memory");   // all publishes ack'd
      __syncthreads();                                   // also guards part[]
      if (tid == 0) {
        store32_sc0(&bar[(g * 32 + rg) * FSTRIDE], (unsigned)(t + 1));
        stA32      (&bar[SLOWOFF + (g * 32 + rg) * FSTRIDE], (unsigned)(t + 1));
      }
      if (tid < 64) {
        int ok = 0;
        if (mode) {
          for (int it = 0; it < TIMEOUT && !ok; ++it) {
            unsigned v = (lane < 32)
                ? poll_sc0(&bar[(g * 32 + lane) * FSTRIDE]) : 0xffffffffu;
            ok = __all((int)(v >= (unsigned)(t + 1)));
          }
        }
        if (!ok) {                 // sticky fallback to proven LLC protocol
          if (tid == 0) modeS = 0u;
          for (;;) {
            unsigned v = (lane < 32)
                ? ldA32(&bar[SLOWOFF + (g * 32 + lane) * FSTRIDE]) : 0xffffffffu;
            if (__all((int)(v >= (unsigned)(t + 1)))) break;
            __builtin_amdgcn_s_sleep(1);
          }
        }
      }
      __syncthreads();
      mode = modeS;                // block-uniform mode for next step's loads
    }
  }
}

// ---- output projection from pack layout: out[b][t][o] ----
__global__ __launch_bounds__(256, 2) void out_proj(
    const unsigned short* __restrict__ hP, const float* __restrict__ WoT,
    const float* __restrict__ b_out, float* __restrict__ out)
{
  const int t = blockIdx.x;
  const int tid = threadIdx.x;
  const int b  = tid & 127;
  const int oh = tid >> 7;                 // wave-uniform output half
  float a0 = b_out[oh * 6 + 0], a1 = b_out[oh * 6 + 1], a2 = b_out[oh * 6 + 2];
  float a3 = b_out[oh * 6 + 3], a4 = b_out[oh * 6 + 4], a5 = b_out[oh * 6 + 5];
  const unsigned short* hp = hP + (size_t)t * HSTEP + (size_t)b * 8;
  const float4* W4 = (const float4*)WoT;
  for (int kb = 0; kb < 128; ++kb) {
    bf16x8 hv = *(const bf16x8*)(hp + (size_t)kb * (B_ * 8));  // 16B coalesced
    #pragma unroll
    for (int j = 0; j < 8; ++j) {
      const int k = kb * 8 + j;
      float h = bf2f((unsigned short)hv[j]);
      float4 wa = W4[k * 4 + oh * 2];       // wave-uniform
      float4 wb = W4[k * 4 + oh * 2 + 1];
      a0 += wa.x * h; a1 += wa.y * h; a2 += wa.z * h;
      a3 += wa.w * h; a4 += wb.x * h; a5 += wb.y * h;
    }
  }
  float* op = out + ((size_t)b * T_ + t) * O_ + oh * 6;
  op[0] = a0; op[1] = a1; op[2] = a2; op[3] = a3; op[4] = a4; op[5] = a5;
}

// ---- host ----
extern "C" void kernel_launch(void* const* d_in, const int* in_sizes, int n_in,
                              void* d_out, int out_size, void* d_ws, size_t ws_size,
                              hipStream_t stream)
{
  const float* x     = (const float*)d_in[0];
  const float* W_ih  = (const float*)d_in[1];
  const float* W_hh  = (const float*)d_in[2];
  const float* b_ih  = (const float*)d_in[3];
  const float* b_hh  = (const float*)d_in[4];
  const float* W_out = (const float*)d_in[5];
  const float* b_out = (const float*)d_in[6];
  float* out = (float*)d_out;

  unsigned short* hP   = (unsigned short*)d_ws;                  // 134.2 MB
  unsigned short* xPhi = hP + (size_t)T_ * HSTEP;                // 8.4 MB
  float*          WoT  = (float*)(xPhi + (size_t)T_ * XSTEP);    // 64 KB
  unsigned short* rF   = (unsigned short*)(WoT + (size_t)H_ * 16); // 512 KB
  unsigned short* rS   = rF + (size_t)8 * 2 * RSLOT;             // 512 KB
  unsigned*       bar  = (unsigned*)(rS + (size_t)8 * 2 * RSLOT); // 64 KB

  prep_xp  <<<T_,  256, 0, stream>>>(x, xPhi);
  prep_misc<<<64,  256, 0, stream>>>(W_out, WoT, bar);
  rnn_mfma <<<256, 256, 0, stream>>>(W_ih, W_hh, b_ih, b_hh, xPhi, hP, rF, rS, bar);
  out_proj <<<T_,  256, 0, stream>>>(hP, WoT, b_out, out);
}